// Round 14
// baseline (104.166 us; speedup 1.0000x reference)
//
#include <hip/hip_runtime.h>
#include <hip/hip_bf16.h>

#define SEQ 394
#define EMB 300
#define EMBP 312                          // 624B rows: 16B-aligned, odd 16B-stride
#define NROWS (64 * SEQ)                  // 25216
#define NCHT 118                          // blob chunks: br0 0..29, br1 30..68, br2 69..117
#define CBE0 29
#define CBE1 68
#define XGR 2691                          // 69 * 39 granules
#define XELEM 21528                       // 69 * 312 elems = 43,056 B

typedef __attribute__((ext_vector_type(8))) short short8;
typedef __attribute__((ext_vector_type(4))) float f32x4;

__device__ __forceinline__ unsigned short f2b(float f) {
    unsigned u = __float_as_uint(f);
    u += 0x7FFFu + ((u >> 16) & 1u);   // RNE to bf16
    return (unsigned short)(u >> 16);
}

// ---------------- pack kernel (W only) ----------------

__global__ __launch_bounds__(256)
void pack_w_kernel(const float* __restrict__ W1, const float* __restrict__ W2,
                   const float* __restrict__ W3, unsigned short* __restrict__ wb)
{
    int G = blockIdx.x * 256 + threadIdx.x;              // 120,832 total (exact)
    int l  = G & 63;
    int g  = (G >> 6) & 15;
    int c  = G >> 10;
    const float* Wg; int n, cb;
    if (c <= CBE0)      { Wg = W1; n = 3; cb = 0;        }
    else if (c <= CBE1) { Wg = W2; n = 4; cb = CBE0 + 1; }
    else                { Wg = W3; n = 5; cb = CBE1 + 1; }
    const int K = n * 300;
    const int f = g * 16 + (l & 15);
    const int kl = (c - cb) * 32 + (l >> 4) * 8;
    unsigned short v[8];
#pragma unroll
    for (int j = 0; j < 8; ++j) {
        int kk = kl + j;
        int r  = kk / EMBP;
        int e  = kk - r * EMBP;
        v[j] = (r < n && e < 300) ? f2b(Wg[(long)f * K + r * 300 + e]) : (unsigned short)0;
    }
    unsigned short* dst = wb + (long)G * 8;
    *(ushort4*)dst       = make_ushort4(v[0], v[1], v[2], v[3]);
    *(ushort4*)(dst + 4) = make_ushort4(v[4], v[5], v[6], v[7]);
}

// ---------------- main kernel ----------------
// Grid 512 = batch(64) x wtile(8 of 49). Block 512 thr = 8 waves = 8 fsets(32f).
// X fp32->bf16 in prologue (69 rows). W global->regs. Cascade with P_mix:
//   P1:  ko 0..38, br1(accA) + br2(accB) share bx        [39 reads, 16 MFMA each]
//   Pmx: ko 39..48 (br2, accB) || ko 0..9 (br0, accA)    [10 iters, 2 indep streams]
//   P0r: ko 10..29, br0 solo (accA)                      [20 reads]
// Weak-solo chunk-reads: 20 (was 40). Same register set as R12 (VGPR ~64).

__global__ __launch_bounds__(512, 5)
void convgemm_kernel(const float* __restrict__ x,
                     const unsigned short* __restrict__ wb,
                     const float* __restrict__ b1, const float* __restrict__ b2,
                     const float* __restrict__ b3,
                     float* __restrict__ out)
{
    __shared__ unsigned short X[XELEM];                  // 43,056 B

    const int tid  = threadIdx.x;
    const int lane = tid & 63;
    const int wfs  = tid >> 6;                           // filter-set 0..7 (32f each)
    const int lr   = lane & 15, lg = lane >> 4;
    const int b    = blockIdx.x >> 3;
    const int ti   = blockIdx.x & 7;
    const int woff = ti * 49;                            // 0,49,...,343

    // ---- W fragment loads: global -> registers, 2 x 16B per wave per chunk ----
    const unsigned short* wp0 = wb + ((long)(wfs * 2) * 64 + lane) * 8;
    auto LDW = [&](int c, short8 (&w)[2]) {
        const short8* p = (const short8*)(wp0 + (long)c * 8192);
        w[0] = p[0];
        w[1] = p[64];
    };

    short8 w1[2], w2[2];
    LDW(30, w1); LDW(69, w2);                            // P1 primes; hide under X conv

    // ---- fused X conversion: fp32 [69 rows x 300] -> bf16 LDS [69 x 312] ----
    {
        const float* xs = x + ((long)b * SEQ + woff) * 300;
        const long growbase = (long)b * SEQ + woff;
#pragma unroll
        for (int rd = 0; rd < 6; ++rd) {
            int gi = rd * 512 + tid;                     // granule 0..2690
            if (gi < XGR) {
                int row = gi / 39;
                int g   = gi - row * 39;
                const float* src = xs + (long)gi * 8 - 12 * row;   // = row*300 + g*8
                float4 v0 = make_float4(0.f, 0.f, 0.f, 0.f);
                float4 v1 = make_float4(0.f, 0.f, 0.f, 0.f);
                if (growbase + row < NROWS) {            // cross-buffer rows zeroed (masked)
                    if (g < 37) {
                        v0 = *(const float4*)src;
                        v1 = *(const float4*)(src + 4);
                    } else if (g == 37) {                // 296..299 real, 300..303 pad
                        v0 = *(const float4*)src;
                    }                                    // g==38: all pad
                }
                short8 s;
                s[0] = (short)f2b(v0.x); s[1] = (short)f2b(v0.y);
                s[2] = (short)f2b(v0.z); s[3] = (short)f2b(v0.w);
                s[4] = (short)f2b(v1.x); s[5] = (short)f2b(v1.y);
                s[6] = (short)f2b(v1.z); s[7] = (short)f2b(v1.w);
                *(short8*)&X[gi * 8] = s;
            }
        }
    }
    __syncthreads();

    // ---- bx reads ----
    const unsigned short* xr = &X[lr * EMBP + lg * 8];
    auto RDBX = [&](int ko, short8 (&bx)[4]) {
        bx[0] = *(const short8*)(xr + ko);
        bx[1] = *(const short8*)(xr + ko + 16 * EMBP);
        bx[2] = *(const short8*)(xr + ko + 32 * EMBP);
        bx[3] = *(const short8*)(xr + ko + 48 * EMBP);
    };

    auto MFMA8 = [&](const short8 (&w)[2], const short8 (&bx)[4], f32x4 (&acc)[2][4]) {
#pragma unroll
        for (int mi = 0; mi < 2; ++mi)
#pragma unroll
            for (int ni = 0; ni < 4; ++ni)
                acc[mi][ni] = __builtin_amdgcn_mfma_f32_16x16x32_bf16(w[mi], bx[ni], acc[mi][ni], 0, 0, 0);
    };

    auto EPI = [&](int br, f32x4 (&acc)[2][4]) {
        const float* bg = (br == 0) ? b1 : (br == 1) ? b2 : b3;
        const int Nw = 391 - br;
        const int ob = b * 768 + br * 256;
#pragma unroll
        for (int mi = 0; mi < 2; ++mi) {
#pragma unroll
            for (int r = 0; r < 4; ++r) {
                const int d = wfs * 32 + mi * 16 + lg * 4 + r;       // C/D row = lg*4+r
                const float bv = bg[d];
                float m = 0.f;
#pragma unroll
                for (int ni = 0; ni < 4; ++ni) {
                    int w = woff + ni * 16 + lr;                     // C/D col = lr
                    float v = fmaxf(acc[mi][ni][r] + bv, 0.f);
                    if (w >= Nw) v = 0.f;
                    m = fmaxf(m, v);
                }
#pragma unroll
                for (int off = 1; off < 16; off <<= 1)
                    m = fmaxf(m, __shfl_xor(m, off));
                if (lr == 0)
                    atomicMax((int*)(out + ob + d), __float_as_int(m));
            }
        }
#pragma unroll
        for (int i = 0; i < 2; ++i)
#pragma unroll
            for (int j = 0; j < 4; ++j)
                acc[i][j] = (f32x4)0.0f;
    };

    f32x4 accA[2][4], accB[2][4];
#pragma unroll
    for (int i = 0; i < 2; ++i)
#pragma unroll
        for (int j = 0; j < 4; ++j) {
            accA[i][j] = (f32x4)0.0f;
            accB[i][j] = (f32x4)0.0f;
        }

    short8 bxA[4], bxB[4];
    RDBX(0, bxA);

    // ======== P1: ko 0..38, br1 (accA) + br2 (accB) share bx ========
    for (int j = 0; j < 38; j += 2) {
        RDBX((j + 1) * 32, bxB);
        MFMA8(w1, bxA, accA);
        MFMA8(w2, bxA, accB);
        LDW(30 + j + 1, w1); LDW(69 + j + 1, w2);

        RDBX((j + 2) * 32, bxA);                         // j+2 <= 38
        MFMA8(w1, bxB, accA);
        MFMA8(w2, bxB, accB);
        LDW(30 + j + 2, w1); LDW(69 + j + 2, w2);
    }
    // tail ko 38 (bxA; w1=blob68, w2=blob107)
    MFMA8(w1, bxA, accA);
    MFMA8(w2, bxA, accB);

    // prime P_mix streams before br1 epilogue (hide L2 latency under EPI)
    LDW(108, w2);                                        // br2 ko 39
    LDW(0, w1);                                          // br0 ko 0
    EPI(1, accA);                                        // accA freed for br0

    // ======== P_mix: br2 tail (ko 39..48, accB) || br0 head (ko 0..9, accA) ========
    for (int t = 0; t < 10; ++t) {
        RDBX((39 + t) * 32, bxB);                        // br2 stream
        RDBX(t * 32, bxA);                               // br0 stream (independent)
        MFMA8(w2, bxB, accB);
        MFMA8(w1, bxA, accA);
        { int u = (109 + t <= 117) ? 109 + t : 117; LDW(u, w2); }
        LDW(1 + t, w1);                                  // t=9 -> blob 10 (P0r prime)
    }

    // prime P0r bx before br2 epilogue
    RDBX(10 * 32, bxA);
    EPI(2, accB);

    // ======== P0r: ko 10..29, br0 solo (accA) ========
    for (int j = 10; j < 30; j += 2) {
        RDBX((j + 1) * 32, bxB);
        MFMA8(w1, bxA, accA);                            // ko j
        LDW(j + 1, w1);

        { int t = (j + 2 <= 29) ? j + 2 : 29; RDBX(t * 32, bxA); }
        MFMA8(w1, bxB, accA);                            // ko j+1
        { int t = (j + 2 <= 29) ? j + 2 : 29; LDW(t, w1); }
    }
    EPI(0, accA);
}

// ---------------- fallback (no-workspace path) ----------------

__device__ __forceinline__ void load_chunk(const float* __restrict__ Wg,
                                           const float* __restrict__ xb,
                                           int K, int dbase, int i0, int k0, int tid,
                                           float4 wv[4], float4 xv[4])
{
#pragma unroll
    for (int i = 0; i < 4; ++i) {
        int fi  = tid + (i << 8);
        int row = fi >> 3;
        int c4  = (fi & 7) << 2;
        int col = k0 + c4;
        if (col < K)
            wv[i] = *(const float4*)(Wg + (long)(dbase + row) * K + col);
        else
            wv[i] = make_float4(0.f, 0.f, 0.f, 0.f);
        int off = (i0 + row) * EMB + col;
        int lim = SEQ * EMB - 4;
        if (off > lim) off = lim;
        xv[i] = *(const float4*)(xb + off);
    }
}

__device__ __forceinline__ void write_chunk(unsigned short (*Wb)[40],
                                            unsigned short (*Xb)[40],
                                            int tid, const float4 wv[4], const float4 xv[4])
{
#pragma unroll
    for (int i = 0; i < 4; ++i) {
        int fi  = tid + (i << 8);
        int row = fi >> 3;
        int c4  = (fi & 7) << 2;
        *(ushort4*)&Wb[row][c4] = make_ushort4(f2b(wv[i].x), f2b(wv[i].y), f2b(wv[i].z), f2b(wv[i].w));
        *(ushort4*)&Xb[row][c4] = make_ushort4(f2b(xv[i].x), f2b(xv[i].y), f2b(xv[i].z), f2b(xv[i].w));
    }
}

__global__ __launch_bounds__(256, 2)
void convmax_fallback(const float* __restrict__ x,
                      const float* __restrict__ W1, const float* __restrict__ W2,
                      const float* __restrict__ W3,
                      const float* __restrict__ b1, const float* __restrict__ b2,
                      const float* __restrict__ b3,
                      float* __restrict__ out)
{
    const int br = blockIdx.z;
    const int K  = (br == 0) ? 900 : (br == 1) ? 1200 : 1500;
    const int Nw = SEQ - 3 - br;
    const float* Wg = (br == 0) ? W1 : (br == 1) ? W2 : W3;
    const float* bg = (br == 0) ? b1 : (br == 1) ? b2 : b3;
    const int b  = blockIdx.x;
    const int mt = blockIdx.y >> 2;
    const int nt = blockIdx.y & 3;
    const int dbase = mt * 128;
    const int i0    = nt * 128;
    const float* xb = x + b * (SEQ * EMB);
    const int nch = (K + 31) >> 5;

    __shared__ unsigned short Wl[2][128][40];
    __shared__ unsigned short Xl[2][128][40];

    const int tid  = threadIdx.x;
    const int lane = tid & 63;
    const int wid  = tid >> 6;
    const int wr = wid >> 1, wc = wid & 1;
    const int lr = lane & 15, lg = lane >> 4;

    f32x4 acc[4][4];
#pragma unroll
    for (int i = 0; i < 4; ++i)
#pragma unroll
        for (int j = 0; j < 4; ++j)
            acc[i][j] = (f32x4)0.0f;

    {
        float4 wv[4], xv[4];
        load_chunk(Wg, xb, K, dbase, i0, 0, tid, wv, xv);
        write_chunk(Wl[0], Xl[0], tid, wv, xv);
    }
    __syncthreads();

    for (int c = 0; c < nch; ++c) {
        const int cur = c & 1;
        float4 wv[4], xv[4];
        const bool pf = (c + 1 < nch);
        if (pf) load_chunk(Wg, xb, K, dbase, i0, (c + 1) << 5, tid, wv, xv);

        short8 af[4], bfr[4];
#pragma unroll
        for (int mi = 0; mi < 4; ++mi)
            af[mi] = *(const short8*)&Wl[cur][wr * 64 + mi * 16 + lr][lg * 8];
#pragma unroll
        for (int ni = 0; ni < 4; ++ni)
            bfr[ni] = *(const short8*)&Xl[cur][wc * 64 + ni * 16 + lr][lg * 8];
#pragma unroll
        for (int mi = 0; mi < 4; ++mi)
#pragma unroll
            for (int ni = 0; ni < 4; ++ni)
                acc[mi][ni] = __builtin_amdgcn_mfma_f32_16x16x32_bf16(af[mi], bfr[ni], acc[mi][ni], 0, 0, 0);

        if (pf) write_chunk(Wl[cur ^ 1], Xl[cur ^ 1], tid, wv, xv);
        __syncthreads();
    }

    const int ob = b * 768 + br * 256;
#pragma unroll
    for (int mi = 0; mi < 4; ++mi) {
#pragma unroll
        for (int rI = 0; rI < 4; ++rI) {
            const int d = dbase + wr * 64 + mi * 16 + lg * 4 + rI;
            const float bv = bg[d];
            float m = 0.f;
#pragma unroll
            for (int ni = 0; ni < 4; ++ni) {
                int win = i0 + wc * 64 + ni * 16 + lr;
                float v = acc[mi][ni][rI] + bv;
                v = fmaxf(v, 0.f);
                if (win >= Nw) v = 0.f;
                m = fmaxf(m, v);
            }
#pragma unroll
            for (int off = 1; off < 16; off <<= 1)
                m = fmaxf(m, __shfl_xor(m, off));
            if (lr == 0)
                atomicMax((int*)(out + ob + d), __float_as_int(m));
        }
    }
}

// ---------------- launch ----------------

extern "C" void kernel_launch(void* const* d_in, const int* in_sizes, int n_in,
                              void* d_out, int out_size, void* d_ws, size_t ws_size,
                              hipStream_t stream) {
    const float* x  = (const float*)d_in[0];
    const float* W1 = (const float*)d_in[1];
    const float* W2 = (const float*)d_in[2];
    const float* W3 = (const float*)d_in[3];
    const float* b1 = (const float*)d_in[4];
    const float* b2 = (const float*)d_in[5];
    const float* b3 = (const float*)d_in[6];
    float* out = (float*)d_out;

    hipMemsetAsync(d_out, 0, (size_t)out_size * sizeof(float), stream);

    const size_t need = (size_t)NCHT * 8192 * 2;         // W blob only: ~1.9 MB

    if (ws_size >= need) {
        unsigned short* wbb = (unsigned short*)d_ws;
        pack_w_kernel<<<472, 256, 0, stream>>>(W1, W2, W3, wbb); // 120,832/256 exact
        convgemm_kernel<<<512, 512, 0, stream>>>(x, wbb, b1, b2, b3, out);
    } else {
        dim3 grid(64, 8, 3);
        convmax_fallback<<<grid, 256, 0, stream>>>(x, W1, W2, W3, b1, b2, b3, out);
    }
}

// Round 15
// 85.379 us; speedup vs baseline: 1.2200x; 1.2200x over previous
//
#include <hip/hip_runtime.h>
#include <hip/hip_bf16.h>

#define SEQ 394
#define EMB 300
#define EMBP 312                          // 624B rows: 16B-aligned, odd 16B-stride
#define NROWS (64 * SEQ)                  // 25216
#define NCHT 118                          // blob chunks: br0 0..29, br1 30..68, br2 69..117
#define CBE0 29
#define CBE1 68
#define XGR 2691                          // 69 * 39 granules
#define XELEM 21528                       // 69 * 312 elems = 43,056 B

typedef __attribute__((ext_vector_type(8))) short short8;
typedef __attribute__((ext_vector_type(4))) float f32x4;

__device__ __forceinline__ unsigned short f2b(float f) {
    unsigned u = __float_as_uint(f);
    u += 0x7FFFu + ((u >> 16) & 1u);   // RNE to bf16
    return (unsigned short)(u >> 16);
}

// ---------------- pack kernel (W only) ----------------

__global__ __launch_bounds__(256)
void pack_w_kernel(const float* __restrict__ W1, const float* __restrict__ W2,
                   const float* __restrict__ W3, unsigned short* __restrict__ wb)
{
    int G = blockIdx.x * 256 + threadIdx.x;              // 120,832 total (exact)
    int l  = G & 63;
    int g  = (G >> 6) & 15;
    int c  = G >> 10;
    const float* Wg; int n, cb;
    if (c <= CBE0)      { Wg = W1; n = 3; cb = 0;        }
    else if (c <= CBE1) { Wg = W2; n = 4; cb = CBE0 + 1; }
    else                { Wg = W3; n = 5; cb = CBE1 + 1; }
    const int K = n * 300;
    const int f = g * 16 + (l & 15);
    const int kl = (c - cb) * 32 + (l >> 4) * 8;
    unsigned short v[8];
#pragma unroll
    for (int j = 0; j < 8; ++j) {
        int kk = kl + j;
        int r  = kk / EMBP;
        int e  = kk - r * EMBP;
        v[j] = (r < n && e < 300) ? f2b(Wg[(long)f * K + r * 300 + e]) : (unsigned short)0;
    }
    unsigned short* dst = wb + (long)G * 8;
    *(ushort4*)dst       = make_ushort4(v[0], v[1], v[2], v[3]);
    *(ushort4*)(dst + 4) = make_ushort4(v[4], v[5], v[6], v[7]);
}

// ---------------- main kernel ----------------
// Grid 512 = batch(64) x wtile(8 of 49). Block 512 thr = 8 waves = 8 fsets(32f).
// launch_bounds(512,4): 128-VGPR budget, no spills (R14's (512,5) spilled: 48 VGPR
// + 57MB scratch writes). X fp32->bf16 in prologue (69 rows). W global->regs.
// Cascade with P_mix:
//   P1:  ko 0..38, br1(accA) + br2(accB) share bx        [39 reads, 16 MFMA each]
//   Pmx: ko 39..48 (br2, accB) || ko 0..9 (br0, accA)    [10 iters, 2 indep streams]
//   P0r: ko 10..29, br0 solo (accA)                      [20 reads]

__global__ __launch_bounds__(512, 4)
void convgemm_kernel(const float* __restrict__ x,
                     const unsigned short* __restrict__ wb,
                     const float* __restrict__ b1, const float* __restrict__ b2,
                     const float* __restrict__ b3,
                     float* __restrict__ out)
{
    __shared__ unsigned short X[XELEM];                  // 43,056 B

    const int tid  = threadIdx.x;
    const int lane = tid & 63;
    const int wfs  = tid >> 6;                           // filter-set 0..7 (32f each)
    const int lr   = lane & 15, lg = lane >> 4;
    const int b    = blockIdx.x >> 3;
    const int ti   = blockIdx.x & 7;
    const int woff = ti * 49;                            // 0,49,...,343

    // ---- W fragment loads: global -> registers, 2 x 16B per wave per chunk ----
    const unsigned short* wp0 = wb + ((long)(wfs * 2) * 64 + lane) * 8;
    auto LDW = [&](int c, short8 (&w)[2]) {
        const short8* p = (const short8*)(wp0 + (long)c * 8192);
        w[0] = p[0];
        w[1] = p[64];
    };

    short8 w1[2], w2[2];
    LDW(30, w1); LDW(69, w2);                            // P1 primes; hide under X conv

    // ---- fused X conversion: fp32 [69 rows x 300] -> bf16 LDS [69 x 312] ----
    {
        const float* xs = x + ((long)b * SEQ + woff) * 300;
        const long growbase = (long)b * SEQ + woff;
#pragma unroll
        for (int rd = 0; rd < 6; ++rd) {
            int gi = rd * 512 + tid;                     // granule 0..2690
            if (gi < XGR) {
                int row = gi / 39;
                int g   = gi - row * 39;
                const float* src = xs + (long)gi * 8 - 12 * row;   // = row*300 + g*8
                float4 v0 = make_float4(0.f, 0.f, 0.f, 0.f);
                float4 v1 = make_float4(0.f, 0.f, 0.f, 0.f);
                if (growbase + row < NROWS) {            // cross-buffer rows zeroed (masked)
                    if (g < 37) {
                        v0 = *(const float4*)src;
                        v1 = *(const float4*)(src + 4);
                    } else if (g == 37) {                // 296..299 real, 300..303 pad
                        v0 = *(const float4*)src;
                    }                                    // g==38: all pad
                }
                short8 s;
                s[0] = (short)f2b(v0.x); s[1] = (short)f2b(v0.y);
                s[2] = (short)f2b(v0.z); s[3] = (short)f2b(v0.w);
                s[4] = (short)f2b(v1.x); s[5] = (short)f2b(v1.y);
                s[6] = (short)f2b(v1.z); s[7] = (short)f2b(v1.w);
                *(short8*)&X[gi * 8] = s;
            }
        }
    }
    __syncthreads();

    // ---- bx reads ----
    const unsigned short* xr = &X[lr * EMBP + lg * 8];
    auto RDBX = [&](int ko, short8 (&bx)[4]) {
        bx[0] = *(const short8*)(xr + ko);
        bx[1] = *(const short8*)(xr + ko + 16 * EMBP);
        bx[2] = *(const short8*)(xr + ko + 32 * EMBP);
        bx[3] = *(const short8*)(xr + ko + 48 * EMBP);
    };

    auto MFMA8 = [&](const short8 (&w)[2], const short8 (&bx)[4], f32x4 (&acc)[2][4]) {
#pragma unroll
        for (int mi = 0; mi < 2; ++mi)
#pragma unroll
            for (int ni = 0; ni < 4; ++ni)
                acc[mi][ni] = __builtin_amdgcn_mfma_f32_16x16x32_bf16(w[mi], bx[ni], acc[mi][ni], 0, 0, 0);
    };

    auto EPI = [&](int br, f32x4 (&acc)[2][4]) {
        const float* bg = (br == 0) ? b1 : (br == 1) ? b2 : b3;
        const int Nw = 391 - br;
        const int ob = b * 768 + br * 256;
#pragma unroll
        for (int mi = 0; mi < 2; ++mi) {
#pragma unroll
            for (int r = 0; r < 4; ++r) {
                const int d = wfs * 32 + mi * 16 + lg * 4 + r;       // C/D row = lg*4+r
                const float bv = bg[d];
                float m = 0.f;
#pragma unroll
                for (int ni = 0; ni < 4; ++ni) {
                    int w = woff + ni * 16 + lr;                     // C/D col = lr
                    float v = fmaxf(acc[mi][ni][r] + bv, 0.f);
                    if (w >= Nw) v = 0.f;
                    m = fmaxf(m, v);
                }
#pragma unroll
                for (int off = 1; off < 16; off <<= 1)
                    m = fmaxf(m, __shfl_xor(m, off));
                if (lr == 0)
                    atomicMax((int*)(out + ob + d), __float_as_int(m));
            }
        }
#pragma unroll
        for (int i = 0; i < 2; ++i)
#pragma unroll
            for (int j = 0; j < 4; ++j)
                acc[i][j] = (f32x4)0.0f;
    };

    f32x4 accA[2][4], accB[2][4];
#pragma unroll
    for (int i = 0; i < 2; ++i)
#pragma unroll
        for (int j = 0; j < 4; ++j) {
            accA[i][j] = (f32x4)0.0f;
            accB[i][j] = (f32x4)0.0f;
        }

    short8 bxA[4], bxB[4];
    RDBX(0, bxA);

    // ======== P1: ko 0..38, br1 (accA) + br2 (accB) share bx ========
    for (int j = 0; j < 38; j += 2) {
        RDBX((j + 1) * 32, bxB);
        MFMA8(w1, bxA, accA);
        MFMA8(w2, bxA, accB);
        LDW(30 + j + 1, w1); LDW(69 + j + 1, w2);

        RDBX((j + 2) * 32, bxA);                         // j+2 <= 38
        MFMA8(w1, bxB, accA);
        MFMA8(w2, bxB, accB);
        LDW(30 + j + 2, w1); LDW(69 + j + 2, w2);
    }
    // tail ko 38 (bxA; w1=blob68, w2=blob107)
    MFMA8(w1, bxA, accA);
    MFMA8(w2, bxA, accB);

    // prime P_mix streams before br1 epilogue (hide L2 latency under EPI)
    LDW(108, w2);                                        // br2 ko 39
    LDW(0, w1);                                          // br0 ko 0
    EPI(1, accA);                                        // accA freed for br0

    // ======== P_mix: br2 tail (ko 39..48, accB) || br0 head (ko 0..9, accA) ========
    for (int t = 0; t < 10; ++t) {
        RDBX((39 + t) * 32, bxB);                        // br2 stream
        RDBX(t * 32, bxA);                               // br0 stream (independent)
        MFMA8(w2, bxB, accB);
        MFMA8(w1, bxA, accA);
        { int u = (109 + t <= 117) ? 109 + t : 117; LDW(u, w2); }
        LDW(1 + t, w1);                                  // t=9 -> blob 10 (P0r prime)
    }

    // prime P0r bx before br2 epilogue
    RDBX(10 * 32, bxA);
    EPI(2, accB);

    // ======== P0r: ko 10..29, br0 solo (accA) ========
    for (int j = 10; j < 30; j += 2) {
        RDBX((j + 1) * 32, bxB);
        MFMA8(w1, bxA, accA);                            // ko j
        LDW(j + 1, w1);

        { int t = (j + 2 <= 29) ? j + 2 : 29; RDBX(t * 32, bxA); }
        MFMA8(w1, bxB, accA);                            // ko j+1
        { int t = (j + 2 <= 29) ? j + 2 : 29; LDW(t, w1); }
    }
    EPI(0, accA);
}

// ---------------- fallback (no-workspace path) ----------------

__device__ __forceinline__ void load_chunk(const float* __restrict__ Wg,
                                           const float* __restrict__ xb,
                                           int K, int dbase, int i0, int k0, int tid,
                                           float4 wv[4], float4 xv[4])
{
#pragma unroll
    for (int i = 0; i < 4; ++i) {
        int fi  = tid + (i << 8);
        int row = fi >> 3;
        int c4  = (fi & 7) << 2;
        int col = k0 + c4;
        if (col < K)
            wv[i] = *(const float4*)(Wg + (long)(dbase + row) * K + col);
        else
            wv[i] = make_float4(0.f, 0.f, 0.f, 0.f);
        int off = (i0 + row) * EMB + col;
        int lim = SEQ * EMB - 4;
        if (off > lim) off = lim;
        xv[i] = *(const float4*)(xb + off);
    }
}

__device__ __forceinline__ void write_chunk(unsigned short (*Wb)[40],
                                            unsigned short (*Xb)[40],
                                            int tid, const float4 wv[4], const float4 xv[4])
{
#pragma unroll
    for (int i = 0; i < 4; ++i) {
        int fi  = tid + (i << 8);
        int row = fi >> 3;
        int c4  = (fi & 7) << 2;
        *(ushort4*)&Wb[row][c4] = make_ushort4(f2b(wv[i].x), f2b(wv[i].y), f2b(wv[i].z), f2b(wv[i].w));
        *(ushort4*)&Xb[row][c4] = make_ushort4(f2b(xv[i].x), f2b(xv[i].y), f2b(xv[i].z), f2b(xv[i].w));
    }
}

__global__ __launch_bounds__(256, 2)
void convmax_fallback(const float* __restrict__ x,
                      const float* __restrict__ W1, const float* __restrict__ W2,
                      const float* __restrict__ W3,
                      const float* __restrict__ b1, const float* __restrict__ b2,
                      const float* __restrict__ b3,
                      float* __restrict__ out)
{
    const int br = blockIdx.z;
    const int K  = (br == 0) ? 900 : (br == 1) ? 1200 : 1500;
    const int Nw = SEQ - 3 - br;
    const float* Wg = (br == 0) ? W1 : (br == 1) ? W2 : W3;
    const float* bg = (br == 0) ? b1 : (br == 1) ? b2 : b3;
    const int b  = blockIdx.x;
    const int mt = blockIdx.y >> 2;
    const int nt = blockIdx.y & 3;
    const int dbase = mt * 128;
    const int i0    = nt * 128;
    const float* xb = x + b * (SEQ * EMB);
    const int nch = (K + 31) >> 5;

    __shared__ unsigned short Wl[2][128][40];
    __shared__ unsigned short Xl[2][128][40];

    const int tid  = threadIdx.x;
    const int lane = tid & 63;
    const int wid  = tid >> 6;
    const int wr = wid >> 1, wc = wid & 1;
    const int lr = lane & 15, lg = lane >> 4;

    f32x4 acc[4][4];
#pragma unroll
    for (int i = 0; i < 4; ++i)
#pragma unroll
        for (int j = 0; j < 4; ++j)
            acc[i][j] = (f32x4)0.0f;

    {
        float4 wv[4], xv[4];
        load_chunk(Wg, xb, K, dbase, i0, 0, tid, wv, xv);
        write_chunk(Wl[0], Xl[0], tid, wv, xv);
    }
    __syncthreads();

    for (int c = 0; c < nch; ++c) {
        const int cur = c & 1;
        float4 wv[4], xv[4];
        const bool pf = (c + 1 < nch);
        if (pf) load_chunk(Wg, xb, K, dbase, i0, (c + 1) << 5, tid, wv, xv);

        short8 af[4], bfr[4];
#pragma unroll
        for (int mi = 0; mi < 4; ++mi)
            af[mi] = *(const short8*)&Wl[cur][wr * 64 + mi * 16 + lr][lg * 8];
#pragma unroll
        for (int ni = 0; ni < 4; ++ni)
            bfr[ni] = *(const short8*)&Xl[cur][wc * 64 + ni * 16 + lr][lg * 8];
#pragma unroll
        for (int mi = 0; mi < 4; ++mi)
#pragma unroll
            for (int ni = 0; ni < 4; ++ni)
                acc[mi][ni] = __builtin_amdgcn_mfma_f32_16x16x32_bf16(af[mi], bfr[ni], acc[mi][ni], 0, 0, 0);

        if (pf) write_chunk(Wl[cur ^ 1], Xl[cur ^ 1], tid, wv, xv);
        __syncthreads();
    }

    const int ob = b * 768 + br * 256;
#pragma unroll
    for (int mi = 0; mi < 4; ++mi) {
#pragma unroll
        for (int rI = 0; rI < 4; ++rI) {
            const int d = dbase + wr * 64 + mi * 16 + lg * 4 + rI;
            const float bv = bg[d];
            float m = 0.f;
#pragma unroll
            for (int ni = 0; ni < 4; ++ni) {
                int win = i0 + wc * 64 + ni * 16 + lr;
                float v = acc[mi][ni][rI] + bv;
                v = fmaxf(v, 0.f);
                if (win >= Nw) v = 0.f;
                m = fmaxf(m, v);
            }
#pragma unroll
            for (int off = 1; off < 16; off <<= 1)
                m = fmaxf(m, __shfl_xor(m, off));
            if (lr == 0)
                atomicMax((int*)(out + ob + d), __float_as_int(m));
        }
    }
}

// ---------------- launch ----------------

extern "C" void kernel_launch(void* const* d_in, const int* in_sizes, int n_in,
                              void* d_out, int out_size, void* d_ws, size_t ws_size,
                              hipStream_t stream) {
    const float* x  = (const float*)d_in[0];
    const float* W1 = (const float*)d_in[1];
    const float* W2 = (const float*)d_in[2];
    const float* W3 = (const float*)d_in[3];
    const float* b1 = (const float*)d_in[4];
    const float* b2 = (const float*)d_in[5];
    const float* b3 = (const float*)d_in[6];
    float* out = (float*)d_out;

    hipMemsetAsync(d_out, 0, (size_t)out_size * sizeof(float), stream);

    const size_t need = (size_t)NCHT * 8192 * 2;         // W blob only: ~1.9 MB

    if (ws_size >= need) {
        unsigned short* wbb = (unsigned short*)d_ws;
        pack_w_kernel<<<472, 256, 0, stream>>>(W1, W2, W3, wbb); // 120,832/256 exact
        convgemm_kernel<<<512, 512, 0, stream>>>(x, wbb, b1, b2, b3, out);
    } else {
        dim3 grid(64, 8, 3);
        convmax_fallback<<<grid, 256, 0, stream>>>(x, W1, W2, W3, b1, b2, b3, out);
    }
}

// Round 16
// 79.845 us; speedup vs baseline: 1.3046x; 1.0693x over previous
//
#include <hip/hip_runtime.h>
#include <hip/hip_bf16.h>

#define SEQ 394
#define EMB 300
#define EMBP 312                          // 624B rows: 16B-aligned, odd 16B-stride
#define NROWS (64 * SEQ)                  // 25216
#define NCHT 118                          // blob chunks: br0 0..29, br1 30..68, br2 69..117
#define CBE0 29
#define CBE1 68
#define RPB 112                           // window-slots (flat rows) per block
#define NBLK 226                          // ceil(25216/112)
#define XROWS 116                         // 112 slots + 4 lookahead (Kp tail)
#define XGR 4524                          // 116 * 39 granules
#define XELEM 36192                       // 116 * 312 elems = 72,384 B
#define NISTR 4992                        // 16 * EMBP: bx ni-stride

typedef __attribute__((ext_vector_type(8))) short short8;
typedef __attribute__((ext_vector_type(4))) float f32x4;

__device__ __forceinline__ unsigned short f2b(float f) {
    unsigned u = __float_as_uint(f);
    u += 0x7FFFu + ((u >> 16) & 1u);   // RNE to bf16
    return (unsigned short)(u >> 16);
}

// ---------------- pack kernel (W only) ----------------

__global__ __launch_bounds__(256)
void pack_w_kernel(const float* __restrict__ W1, const float* __restrict__ W2,
                   const float* __restrict__ W3, unsigned short* __restrict__ wb)
{
    int G = blockIdx.x * 256 + threadIdx.x;              // 120,832 total (exact)
    int l  = G & 63;
    int g  = (G >> 6) & 15;
    int c  = G >> 10;
    const float* Wg; int n, cb;
    if (c <= CBE0)      { Wg = W1; n = 3; cb = 0;        }
    else if (c <= CBE1) { Wg = W2; n = 4; cb = CBE0 + 1; }
    else                { Wg = W3; n = 5; cb = CBE1 + 1; }
    const int K = n * 300;
    const int f = g * 16 + (l & 15);
    const int kl = (c - cb) * 32 + (l >> 4) * 8;
    unsigned short v[8];
#pragma unroll
    for (int j = 0; j < 8; ++j) {
        int kk = kl + j;
        int r  = kk / EMBP;
        int e  = kk - r * EMBP;
        v[j] = (r < n && e < 300) ? f2b(Wg[(long)f * K + r * 300 + e]) : (unsigned short)0;
    }
    unsigned short* dst = wb + (long)G * 8;
    *(ushort4*)dst       = make_ushort4(v[0], v[1], v[2], v[3]);
    *(ushort4*)(dst + 4) = make_ushort4(v[4], v[5], v[6], v[7]);
}

// ---------------- main kernel ----------------
// BATCH-MERGED flat-row tiling: grid 226, block = rows r0 = blk*112 .. +111 (slot
// waste ~0.4% vs R12's 24%). 512 thr = 8 waves = 8 fsets(32f) x 112 windows (7 ni).
// X fp32->bf16 into LDS (116 rows, 72KB). W global->regs (frag blob, as R12).
// Cascade: P1 br1+br2 share bx ko 0..38; P2 br2 solo 39..48; P0 br0 solo 0..29.
// Epilogue: <=1 batch boundary per block -> segmented vlo/vhi max (R2 pattern).
// launch_bounds(512,2): acc[2][7]x2 + bx[7]x2 ~ 210 VGPR, no spill (R14 lesson).

__global__ __launch_bounds__(512, 2)
void convgemm_kernel(const float* __restrict__ x,
                     const unsigned short* __restrict__ wb,
                     const float* __restrict__ b1, const float* __restrict__ b2,
                     const float* __restrict__ b3,
                     float* __restrict__ out)
{
    __shared__ unsigned short X[XELEM];                  // 72,384 B

    const int tid  = threadIdx.x;
    const int lane = tid & 63;
    const int wfs  = tid >> 6;                           // filter-set 0..7 (32f each)
    const int lr   = lane & 15, lg = lane >> 4;
    const long r0  = (long)blockIdx.x * RPB;

    // ---- W fragment loads: global -> registers, 2 x 16B per wave per chunk ----
    const unsigned short* wp0 = wb + ((long)(wfs * 2) * 64 + lane) * 8;
    auto LDW = [&](int c, short8 (&w)[2]) {
        const short8* p = (const short8*)(wp0 + (long)c * 8192);
        w[0] = p[0];
        w[1] = p[64];
    };

    short8 w1[2], w2[2];
    LDW(30, w1); LDW(69, w2);                            // P1 primes; hide under X conv

    // ---- fused X conversion: fp32 [116 rows x 300] -> bf16 LDS [116 x 312] ----
    {
        const float* xs = x + r0 * 300;                  // r0*300 float4-aligned
#pragma unroll
        for (int rd = 0; rd < 9; ++rd) {
            int gi = rd * 512 + tid;                     // granule 0..4523
            if (gi < XGR) {
                int row = gi / 39;
                int g   = gi - row * 39;
                const float* src = xs + (long)gi * 8 - 12 * row;   // = row*300 + g*8
                float4 v0 = make_float4(0.f, 0.f, 0.f, 0.f);
                float4 v1 = make_float4(0.f, 0.f, 0.f, 0.f);
                if (r0 + row < NROWS) {                  // rows past buffer end zeroed
                    if (g < 37) {
                        v0 = *(const float4*)src;
                        v1 = *(const float4*)(src + 4);
                    } else if (g == 37) {                // 296..299 real, 300..303 pad
                        v0 = *(const float4*)src;
                    }                                    // g==38: all pad
                }
                short8 s;
                s[0] = (short)f2b(v0.x); s[1] = (short)f2b(v0.y);
                s[2] = (short)f2b(v0.z); s[3] = (short)f2b(v0.w);
                s[4] = (short)f2b(v1.x); s[5] = (short)f2b(v1.y);
                s[6] = (short)f2b(v1.z); s[7] = (short)f2b(v1.w);
                *(short8*)&X[gi * 8] = s;
            }
        }
    }
    __syncthreads();

    // ---- bx reads: slot = ni*16+lr; addr = slot*312 + ko + lg*8 (flat k-span) ----
    const unsigned short* xr = &X[lr * EMBP + lg * 8];
    auto RDBX = [&](int ko, short8 (&bx)[7]) {
#pragma unroll
        for (int ni = 0; ni < 7; ++ni)
            bx[ni] = *(const short8*)(xr + ko + ni * NISTR);
    };

    auto MFMA14 = [&](const short8 (&w)[2], const short8 (&bx)[7], f32x4 (&acc)[2][7]) {
#pragma unroll
        for (int mi = 0; mi < 2; ++mi)
#pragma unroll
            for (int ni = 0; ni < 7; ++ni)
                acc[mi][ni] = __builtin_amdgcn_mfma_f32_16x16x32_bf16(w[mi], bx[ni], acc[mi][ni], 0, 0, 0);
    };

    // segmented epilogue: block spans <=1 batch boundary
    const int  B0  = (int)(r0 / SEQ);                    // wave-uniform; <= 63
    const long rB1 = (long)(B0 + 1) * SEQ;               // first row of next batch
    const bool cross = (r0 + RPB - 1) >= rB1;

    auto EPI = [&](int br, f32x4 (&acc)[2][7]) {
        const float* bg = (br == 0) ? b1 : (br == 1) ? b2 : b3;
        const int Nw = 391 - br;
#pragma unroll
        for (int mi = 0; mi < 2; ++mi) {
#pragma unroll
            for (int r = 0; r < 4; ++r) {
                const int d = wfs * 32 + mi * 16 + lg * 4 + r;       // C/D row = lg*4+r
                const float bv = bg[d];
                float vlo = 0.f, vhi = 0.f;
#pragma unroll
                for (int ni = 0; ni < 7; ++ni) {
                    long rr = r0 + ni * 16 + lr;                     // C/D col = lr
                    bool hi = rr >= rB1;
                    long ii = rr - (hi ? rB1 : (long)B0 * SEQ);      // batch-local window
                    float v = fmaxf(acc[mi][ni][r] + bv, 0.f);
                    if (ii >= Nw || (hi && B0 + 1 >= 64)) v = 0.f;
                    vlo = hi ? vlo : fmaxf(vlo, v);
                    vhi = hi ? fmaxf(vhi, v) : vhi;
                }
#pragma unroll
                for (int off = 1; off < 16; off <<= 1) {
                    vlo = fmaxf(vlo, __shfl_xor(vlo, off));
                    vhi = fmaxf(vhi, __shfl_xor(vhi, off));
                }
                if (lr == 0) {
                    atomicMax((int*)(out + (long)B0 * 768 + br * 256 + d), __float_as_int(vlo));
                    if (cross && B0 + 1 < 64)
                        atomicMax((int*)(out + (long)(B0 + 1) * 768 + br * 256 + d), __float_as_int(vhi));
                }
            }
        }
#pragma unroll
        for (int i = 0; i < 2; ++i)
#pragma unroll
            for (int j = 0; j < 7; ++j)
                acc[i][j] = (f32x4)0.0f;
    };

    f32x4 accA[2][7], accB[2][7];
#pragma unroll
    for (int i = 0; i < 2; ++i)
#pragma unroll
        for (int j = 0; j < 7; ++j) {
            accA[i][j] = (f32x4)0.0f;
            accB[i][j] = (f32x4)0.0f;
        }

    short8 bxA[7], bxB[7];
    RDBX(0, bxA);

    // ======== P1: ko 0..38, br1 (accA) + br2 (accB) share bx ========
    for (int j = 0; j < 38; j += 2) {
        RDBX((j + 1) * 32, bxB);
        MFMA14(w1, bxA, accA);
        MFMA14(w2, bxA, accB);
        LDW(30 + j + 1, w1); LDW(69 + j + 1, w2);

        RDBX((j + 2) * 32, bxA);                         // j+2 <= 38
        MFMA14(w1, bxB, accA);
        MFMA14(w2, bxB, accB);
        LDW(30 + j + 2, w1); LDW(69 + j + 2, w2);
    }
    // tail ko 38 (bxA; w1=blob68, w2=blob107)
    MFMA14(w1, bxA, accA);
    MFMA14(w2, bxA, accB);

    // prime P2 (w2 <- blob108 = ko39; bxB <- ko39) before br1 epilogue
    LDW(108, w2);
    RDBX(39 * 32, bxB);
    EPI(1, accA);                                        // accA freed for br0

    // ======== P2: ko 39..48, br2 solo (accB) ========
    for (int u = 0; u < 10; u += 2) {
        RDBX((40 + u) * 32, bxA);                        // <= 48
        MFMA14(w2, bxB, accB);                           // ko 39+u
        LDW(109 + u, w2);                                // ko 40+u

        { int t = (41 + u <= 48) ? 41 + u : 48; RDBX(t * 32, bxB); }
        MFMA14(w2, bxA, accB);                           // ko 40+u
        { int t = (110 + u <= 117) ? 110 + u : 117; LDW(t, w2); }
    }

    // prime P0 (w1 <- blob0; bxA <- ko0) before br2 epilogue
    LDW(0, w1);
    RDBX(0, bxA);
    EPI(2, accB);

    // ======== P0: ko 0..29, br0 solo (accA) ========
    for (int j = 0; j < 30; j += 2) {
        RDBX((j + 1) * 32, bxB);
        MFMA14(w1, bxA, accA);                           // ko j
        LDW(j + 1, w1);

        { int t = (j + 2 <= 29) ? j + 2 : 29; RDBX(t * 32, bxA); }
        MFMA14(w1, bxB, accA);                           // ko j+1
        { int t = (j + 2 <= 29) ? j + 2 : 29; LDW(t, w1); }
    }
    EPI(0, accA);
}

// ---------------- fallback (no-workspace path) ----------------

__device__ __forceinline__ void load_chunk(const float* __restrict__ Wg,
                                           const float* __restrict__ xb,
                                           int K, int dbase, int i0, int k0, int tid,
                                           float4 wv[4], float4 xv[4])
{
#pragma unroll
    for (int i = 0; i < 4; ++i) {
        int fi  = tid + (i << 8);
        int row = fi >> 3;
        int c4  = (fi & 7) << 2;
        int col = k0 + c4;
        if (col < K)
            wv[i] = *(const float4*)(Wg + (long)(dbase + row) * K + col);
        else
            wv[i] = make_float4(0.f, 0.f, 0.f, 0.f);
        int off = (i0 + row) * EMB + col;
        int lim = SEQ * EMB - 4;
        if (off > lim) off = lim;
        xv[i] = *(const float4*)(xb + off);
    }
}

__device__ __forceinline__ void write_chunk(unsigned short (*Wb)[40],
                                            unsigned short (*Xb)[40],
                                            int tid, const float4 wv[4], const float4 xv[4])
{
#pragma unroll
    for (int i = 0; i < 4; ++i) {
        int fi  = tid + (i << 8);
        int row = fi >> 3;
        int c4  = (fi & 7) << 2;
        *(ushort4*)&Wb[row][c4] = make_ushort4(f2b(wv[i].x), f2b(wv[i].y), f2b(wv[i].z), f2b(wv[i].w));
        *(ushort4*)&Xb[row][c4] = make_ushort4(f2b(xv[i].x), f2b(xv[i].y), f2b(xv[i].z), f2b(xv[i].w));
    }
}

__global__ __launch_bounds__(256, 2)
void convmax_fallback(const float* __restrict__ x,
                      const float* __restrict__ W1, const float* __restrict__ W2,
                      const float* __restrict__ W3,
                      const float* __restrict__ b1, const float* __restrict__ b2,
                      const float* __restrict__ b3,
                      float* __restrict__ out)
{
    const int br = blockIdx.z;
    const int K  = (br == 0) ? 900 : (br == 1) ? 1200 : 1500;
    const int Nw = SEQ - 3 - br;
    const float* Wg = (br == 0) ? W1 : (br == 1) ? W2 : W3;
    const float* bg = (br == 0) ? b1 : (br == 1) ? b2 : b3;
    const int b  = blockIdx.x;
    const int mt = blockIdx.y >> 2;
    const int nt = blockIdx.y & 3;
    const int dbase = mt * 128;
    const int i0    = nt * 128;
    const float* xb = x + b * (SEQ * EMB);
    const int nch = (K + 31) >> 5;

    __shared__ unsigned short Wl[2][128][40];
    __shared__ unsigned short Xl[2][128][40];

    const int tid  = threadIdx.x;
    const int lane = tid & 63;
    const int wid  = tid >> 6;
    const int wr = wid >> 1, wc = wid & 1;
    const int lr = lane & 15, lg = lane >> 4;

    f32x4 acc[4][4];
#pragma unroll
    for (int i = 0; i < 4; ++i)
#pragma unroll
        for (int j = 0; j < 4; ++j)
            acc[i][j] = (f32x4)0.0f;

    {
        float4 wv[4], xv[4];
        load_chunk(Wg, xb, K, dbase, i0, 0, tid, wv, xv);
        write_chunk(Wl[0], Xl[0], tid, wv, xv);
    }
    __syncthreads();

    for (int c = 0; c < nch; ++c) {
        const int cur = c & 1;
        float4 wv[4], xv[4];
        const bool pf = (c + 1 < nch);
        if (pf) load_chunk(Wg, xb, K, dbase, i0, (c + 1) << 5, tid, wv, xv);

        short8 af[4], bfr[4];
#pragma unroll
        for (int mi = 0; mi < 4; ++mi)
            af[mi] = *(const short8*)&Wl[cur][wr * 64 + mi * 16 + lr][lg * 8];
#pragma unroll
        for (int ni = 0; ni < 4; ++ni)
            bfr[ni] = *(const short8*)&Xl[cur][wc * 64 + ni * 16 + lr][lg * 8];
#pragma unroll
        for (int mi = 0; mi < 4; ++mi)
#pragma unroll
            for (int ni = 0; ni < 4; ++ni)
                acc[mi][ni] = __builtin_amdgcn_mfma_f32_16x16x32_bf16(af[mi], bfr[ni], acc[mi][ni], 0, 0, 0);

        if (pf) write_chunk(Wl[cur ^ 1], Xl[cur ^ 1], tid, wv, xv);
        __syncthreads();
    }

    const int ob = b * 768 + br * 256;
#pragma unroll
    for (int mi = 0; mi < 4; ++mi) {
#pragma unroll
        for (int rI = 0; rI < 4; ++rI) {
            const int d = dbase + wr * 64 + mi * 16 + lg * 4 + rI;
            const float bv = bg[d];
            float m = 0.f;
#pragma unroll
            for (int ni = 0; ni < 4; ++ni) {
                int win = i0 + wc * 64 + ni * 16 + lr;
                float v = acc[mi][ni][rI] + bv;
                v = fmaxf(v, 0.f);
                if (win >= Nw) v = 0.f;
                m = fmaxf(m, v);
            }
#pragma unroll
            for (int off = 1; off < 16; off <<= 1)
                m = fmaxf(m, __shfl_xor(m, off));
            if (lr == 0)
                atomicMax((int*)(out + ob + d), __float_as_int(m));
        }
    }
}

// ---------------- launch ----------------

extern "C" void kernel_launch(void* const* d_in, const int* in_sizes, int n_in,
                              void* d_out, int out_size, void* d_ws, size_t ws_size,
                              hipStream_t stream) {
    const float* x  = (const float*)d_in[0];
    const float* W1 = (const float*)d_in[1];
    const float* W2 = (const float*)d_in[2];
    const float* W3 = (const float*)d_in[3];
    const float* b1 = (const float*)d_in[4];
    const float* b2 = (const float*)d_in[5];
    const float* b3 = (const float*)d_in[6];
    float* out = (float*)d_out;

    hipMemsetAsync(d_out, 0, (size_t)out_size * sizeof(float), stream);

    const size_t need = (size_t)NCHT * 8192 * 2;         // W blob only: ~1.9 MB

    if (ws_size >= need) {
        unsigned short* wbb = (unsigned short*)d_ws;
        pack_w_kernel<<<472, 256, 0, stream>>>(W1, W2, W3, wbb); // 120,832/256 exact
        convgemm_kernel<<<NBLK, 512, 0, stream>>>(x, wbb, b1, b2, b3, out);
    } else {
        dim3 grid(64, 8, 3);
        convmax_fallback<<<grid, 256, 0, stream>>>(x, W1, W2, W3, b1, b2, b3, out);
    }
}

// Round 17
// 76.404 us; speedup vs baseline: 1.3634x; 1.0450x over previous
//
#include <hip/hip_runtime.h>
#include <hip/hip_bf16.h>

#define SEQ 394
#define EMB 300
#define EMBP 312                          // 624B rows: 16B-aligned, odd 16B-stride
#define NROWS (64 * SEQ)                  // 25216
#define NCHT 118                          // blob chunks: br0 0..29, br1 30..68, br2 69..117
#define CBE0 29
#define CBE1 68
#define RPB 128                           // slots per block: 25216 = 197 * 128 EXACT
#define NBLK 197
#define XROWS 132                         // 128 slots + 4 lookahead
#define XGR 5148                          // 132 * 39 granules
#define XELEM 41184                       // 132 * 312 elems = 82,368 B

typedef __attribute__((ext_vector_type(8))) short short8;
typedef __attribute__((ext_vector_type(4))) float f32x4;

__device__ __forceinline__ unsigned short f2b(float f) {
    unsigned u = __float_as_uint(f);
    u += 0x7FFFu + ((u >> 16) & 1u);   // RNE to bf16
    return (unsigned short)(u >> 16);
}

// ---------------- pack kernel (W only) ----------------

__global__ __launch_bounds__(256)
void pack_w_kernel(const float* __restrict__ W1, const float* __restrict__ W2,
                   const float* __restrict__ W3, unsigned short* __restrict__ wb)
{
    int G = blockIdx.x * 256 + threadIdx.x;              // 120,832 total (exact)
    int l  = G & 63;
    int g  = (G >> 6) & 15;
    int c  = G >> 10;
    const float* Wg; int n, cb;
    if (c <= CBE0)      { Wg = W1; n = 3; cb = 0;        }
    else if (c <= CBE1) { Wg = W2; n = 4; cb = CBE0 + 1; }
    else                { Wg = W3; n = 5; cb = CBE1 + 1; }
    const int K = n * 300;
    const int f = g * 16 + (l & 15);
    const int kl = (c - cb) * 32 + (l >> 4) * 8;
    unsigned short v[8];
#pragma unroll
    for (int j = 0; j < 8; ++j) {
        int kk = kl + j;
        int r  = kk / EMBP;
        int e  = kk - r * EMBP;
        v[j] = (r < n && e < 300) ? f2b(Wg[(long)f * K + r * 300 + e]) : (unsigned short)0;
    }
    unsigned short* dst = wb + (long)G * 8;
    *(ushort4*)dst       = make_ushort4(v[0], v[1], v[2], v[3]);
    *(ushort4*)(dst + 4) = make_ushort4(v[4], v[5], v[6], v[7]);
}

// ---------------- main kernel ----------------
// ONE ROUND, ZERO WASTE: grid 197 = 25216/128 exact; block = flat rows r0..r0+127.
// 1024 thr = 16 waves = 8 fsets(32f) x 2 wsets(64w); 4 waves/SIMD (R8/R9's proven
// issue capacity). X fp32->bf16 in prologue (132 rows, 82KB). W global->regs.
// Cascade: P1 br1+br2 share bx ko 0..38; P2 br2 solo 39..48; P0 br0 solo 0..29.
// Segmented epilogue handles the <=1 batch boundary per block.

__global__ __launch_bounds__(1024, 1)
void convgemm_kernel(const float* __restrict__ x,
                     const unsigned short* __restrict__ wb,
                     const float* __restrict__ b1, const float* __restrict__ b2,
                     const float* __restrict__ b3,
                     float* __restrict__ out)
{
    __shared__ unsigned short X[XELEM];                  // 82,368 B

    const int tid  = threadIdx.x;
    const int lane = tid & 63;
    const int wid  = tid >> 6;
    const int wfs  = wid >> 1;                           // filter-set 0..7 (32f each)
    const int ws   = wid & 1;                            // window-set 0..1 (64 slots each)
    const int lr   = lane & 15, lg = lane >> 4;
    const long r0  = (long)blockIdx.x * RPB;

    // ---- W fragment loads: global -> registers, 2 x 16B per wave per chunk ----
    const unsigned short* wp0 = wb + ((long)(wfs * 2) * 64 + lane) * 8;
    auto LDW = [&](int c, short8 (&w)[2]) {
        const short8* p = (const short8*)(wp0 + (long)c * 8192);
        w[0] = p[0];
        w[1] = p[64];
    };

    short8 w1[2], w2[2];
    LDW(30, w1); LDW(69, w2);                            // P1 primes; hide under X conv

    // ---- fused X conversion: fp32 [132 rows x 300] -> bf16 LDS [132 x 312] ----
    {
        const float* xs = x + r0 * 300;
#pragma unroll
        for (int rd = 0; rd < 6; ++rd) {
            int gi = rd * 1024 + tid;                    // granule 0..5147
            if (gi < XGR) {
                int row = gi / 39;
                int g   = gi - row * 39;
                const float* src = xs + (long)gi * 8 - 12 * row;   // = row*300 + g*8
                float4 v0 = make_float4(0.f, 0.f, 0.f, 0.f);
                float4 v1 = make_float4(0.f, 0.f, 0.f, 0.f);
                if (r0 + row < NROWS) {                  // rows past buffer end zeroed
                    if (g < 37) {
                        v0 = *(const float4*)src;
                        v1 = *(const float4*)(src + 4);
                    } else if (g == 37) {                // 296..299 real, 300..303 pad
                        v0 = *(const float4*)src;
                    }                                    // g==38: all pad
                }
                short8 s;
                s[0] = (short)f2b(v0.x); s[1] = (short)f2b(v0.y);
                s[2] = (short)f2b(v0.z); s[3] = (short)f2b(v0.w);
                s[4] = (short)f2b(v1.x); s[5] = (short)f2b(v1.y);
                s[6] = (short)f2b(v1.z); s[7] = (short)f2b(v1.w);
                *(short8*)&X[gi * 8] = s;
            }
        }
    }
    __syncthreads();

    // ---- bx reads: slot = ws*64 + ni*16 + lr; addr = slot*312 + ko + lg*8 ----
    const unsigned short* xr = &X[(ws * 64 + lr) * EMBP + lg * 8];
    auto RDBX = [&](int ko, short8 (&bx)[4]) {
        bx[0] = *(const short8*)(xr + ko);
        bx[1] = *(const short8*)(xr + ko + 16 * EMBP);
        bx[2] = *(const short8*)(xr + ko + 32 * EMBP);
        bx[3] = *(const short8*)(xr + ko + 48 * EMBP);
    };

    auto MFMA8 = [&](const short8 (&w)[2], const short8 (&bx)[4], f32x4 (&acc)[2][4]) {
#pragma unroll
        for (int mi = 0; mi < 2; ++mi)
#pragma unroll
            for (int ni = 0; ni < 4; ++ni)
                acc[mi][ni] = __builtin_amdgcn_mfma_f32_16x16x32_bf16(w[mi], bx[ni], acc[mi][ni], 0, 0, 0);
    };

    // segmented epilogue: block spans <=1 batch boundary
    const int  B0  = (int)(r0 / SEQ);                    // block-uniform
    const long rB1 = (long)(B0 + 1) * SEQ;
    const bool cross = (r0 + RPB - 1) >= rB1;

    auto EPI = [&](int br, f32x4 (&acc)[2][4]) {
        const float* bg = (br == 0) ? b1 : (br == 1) ? b2 : b3;
        const int Nw = 391 - br;
#pragma unroll
        for (int mi = 0; mi < 2; ++mi) {
#pragma unroll
            for (int r = 0; r < 4; ++r) {
                const int d = wfs * 32 + mi * 16 + lg * 4 + r;       // C/D row = lg*4+r
                const float bv = bg[d];
                float vlo = 0.f, vhi = 0.f;
#pragma unroll
                for (int ni = 0; ni < 4; ++ni) {
                    long rr = r0 + ws * 64 + ni * 16 + lr;           // C/D col = lr
                    bool hi = rr >= rB1;
                    long ii = rr - (hi ? rB1 : (long)B0 * SEQ);      // batch-local window
                    float v = fmaxf(acc[mi][ni][r] + bv, 0.f);
                    if (ii >= Nw) v = 0.f;
                    vlo = hi ? vlo : fmaxf(vlo, v);
                    vhi = hi ? fmaxf(vhi, v) : vhi;
                }
#pragma unroll
                for (int off = 1; off < 16; off <<= 1) {
                    vlo = fmaxf(vlo, __shfl_xor(vlo, off));
                    vhi = fmaxf(vhi, __shfl_xor(vhi, off));
                }
                if (lr == 0) {
                    atomicMax((int*)(out + (long)B0 * 768 + br * 256 + d), __float_as_int(vlo));
                    if (cross && B0 + 1 < 64)
                        atomicMax((int*)(out + (long)(B0 + 1) * 768 + br * 256 + d), __float_as_int(vhi));
                }
            }
        }
#pragma unroll
        for (int i = 0; i < 2; ++i)
#pragma unroll
            for (int j = 0; j < 4; ++j)
                acc[i][j] = (f32x4)0.0f;
    };

    f32x4 accA[2][4], accB[2][4];
#pragma unroll
    for (int i = 0; i < 2; ++i)
#pragma unroll
        for (int j = 0; j < 4; ++j) {
            accA[i][j] = (f32x4)0.0f;
            accB[i][j] = (f32x4)0.0f;
        }

    short8 bxA[4], bxB[4];
    RDBX(0, bxA);

    // ======== P1: ko 0..38, br1 (accA) + br2 (accB) share bx ========
    for (int j = 0; j < 38; j += 2) {
        RDBX((j + 1) * 32, bxB);
        MFMA8(w1, bxA, accA);
        MFMA8(w2, bxA, accB);
        LDW(30 + j + 1, w1); LDW(69 + j + 1, w2);

        RDBX((j + 2) * 32, bxA);                         // j+2 <= 38
        MFMA8(w1, bxB, accA);
        MFMA8(w2, bxB, accB);
        LDW(30 + j + 2, w1); LDW(69 + j + 2, w2);
    }
    // tail ko 38 (bxA; w1=blob68, w2=blob107)
    MFMA8(w1, bxA, accA);
    MFMA8(w2, bxA, accB);

    // prime P2 (w2 <- blob108 = ko39; bxB <- ko39) before br1 epilogue
    LDW(108, w2);
    RDBX(39 * 32, bxB);
    EPI(1, accA);                                        // accA freed for br0

    // ======== P2: ko 39..48, br2 solo (accB) ========
    for (int u = 0; u < 10; u += 2) {
        RDBX((40 + u) * 32, bxA);                        // <= 48
        MFMA8(w2, bxB, accB);                            // ko 39+u
        LDW(109 + u, w2);                                // ko 40+u

        { int t = (41 + u <= 48) ? 41 + u : 48; RDBX(t * 32, bxB); }
        MFMA8(w2, bxA, accB);                            // ko 40+u
        { int t = (110 + u <= 117) ? 110 + u : 117; LDW(t, w2); }
    }

    // prime P0 (w1 <- blob0; bxA <- ko0) before br2 epilogue
    LDW(0, w1);
    RDBX(0, bxA);
    EPI(2, accB);

    // ======== P0: ko 0..29, br0 solo (accA) ========
    for (int j = 0; j < 30; j += 2) {
        RDBX((j + 1) * 32, bxB);
        MFMA8(w1, bxA, accA);                            // ko j
        LDW(j + 1, w1);

        { int t = (j + 2 <= 29) ? j + 2 : 29; RDBX(t * 32, bxA); }
        MFMA8(w1, bxB, accA);                            // ko j+1
        { int t = (j + 2 <= 29) ? j + 2 : 29; LDW(t, w1); }
    }
    EPI(0, accA);
}

// ---------------- fallback (no-workspace path) ----------------

__device__ __forceinline__ void load_chunk(const float* __restrict__ Wg,
                                           const float* __restrict__ xb,
                                           int K, int dbase, int i0, int k0, int tid,
                                           float4 wv[4], float4 xv[4])
{
#pragma unroll
    for (int i = 0; i < 4; ++i) {
        int fi  = tid + (i << 8);
        int row = fi >> 3;
        int c4  = (fi & 7) << 2;
        int col = k0 + c4;
        if (col < K)
            wv[i] = *(const float4*)(Wg + (long)(dbase + row) * K + col);
        else
            wv[i] = make_float4(0.f, 0.f, 0.f, 0.f);
        int off = (i0 + row) * EMB + col;
        int lim = SEQ * EMB - 4;
        if (off > lim) off = lim;
        xv[i] = *(const float4*)(xb + off);
    }
}

__device__ __forceinline__ void write_chunk(unsigned short (*Wb)[40],
                                            unsigned short (*Xb)[40],
                                            int tid, const float4 wv[4], const float4 xv[4])
{
#pragma unroll
    for (int i = 0; i < 4; ++i) {
        int fi  = tid + (i << 8);
        int row = fi >> 3;
        int c4  = (fi & 7) << 2;
        *(ushort4*)&Wb[row][c4] = make_ushort4(f2b(wv[i].x), f2b(wv[i].y), f2b(wv[i].z), f2b(wv[i].w));
        *(ushort4*)&Xb[row][c4] = make_ushort4(f2b(xv[i].x), f2b(xv[i].y), f2b(xv[i].z), f2b(xv[i].w));
    }
}

__global__ __launch_bounds__(256, 2)
void convmax_fallback(const float* __restrict__ x,
                      const float* __restrict__ W1, const float* __restrict__ W2,
                      const float* __restrict__ W3,
                      const float* __restrict__ b1, const float* __restrict__ b2,
                      const float* __restrict__ b3,
                      float* __restrict__ out)
{
    const int br = blockIdx.z;
    const int K  = (br == 0) ? 900 : (br == 1) ? 1200 : 1500;
    const int Nw = SEQ - 3 - br;
    const float* Wg = (br == 0) ? W1 : (br == 1) ? W2 : W3;
    const float* bg = (br == 0) ? b1 : (br == 1) ? b2 : b3;
    const int b  = blockIdx.x;
    const int mt = blockIdx.y >> 2;
    const int nt = blockIdx.y & 3;
    const int dbase = mt * 128;
    const int i0    = nt * 128;
    const float* xb = x + b * (SEQ * EMB);
    const int nch = (K + 31) >> 5;

    __shared__ unsigned short Wl[2][128][40];
    __shared__ unsigned short Xl[2][128][40];

    const int tid  = threadIdx.x;
    const int lane = tid & 63;
    const int wid  = tid >> 6;
    const int wr = wid >> 1, wc = wid & 1;
    const int lr = lane & 15, lg = lane >> 4;

    f32x4 acc[4][4];
#pragma unroll
    for (int i = 0; i < 4; ++i)
#pragma unroll
        for (int j = 0; j < 4; ++j)
            acc[i][j] = (f32x4)0.0f;

    {
        float4 wv[4], xv[4];
        load_chunk(Wg, xb, K, dbase, i0, 0, tid, wv, xv);
        write_chunk(Wl[0], Xl[0], tid, wv, xv);
    }
    __syncthreads();

    for (int c = 0; c < nch; ++c) {
        const int cur = c & 1;
        float4 wv[4], xv[4];
        const bool pf = (c + 1 < nch);
        if (pf) load_chunk(Wg, xb, K, dbase, i0, (c + 1) << 5, tid, wv, xv);

        short8 af[4], bfr[4];
#pragma unroll
        for (int mi = 0; mi < 4; ++mi)
            af[mi] = *(const short8*)&Wl[cur][wr * 64 + mi * 16 + lr][lg * 8];
#pragma unroll
        for (int ni = 0; ni < 4; ++ni)
            bfr[ni] = *(const short8*)&Xl[cur][wc * 64 + ni * 16 + lr][lg * 8];
#pragma unroll
        for (int mi = 0; mi < 4; ++mi)
#pragma unroll
            for (int ni = 0; ni < 4; ++ni)
                acc[mi][ni] = __builtin_amdgcn_mfma_f32_16x16x32_bf16(af[mi], bfr[ni], acc[mi][ni], 0, 0, 0);

        if (pf) write_chunk(Wl[cur ^ 1], Xl[cur ^ 1], tid, wv, xv);
        __syncthreads();
    }

    const int ob = b * 768 + br * 256;
#pragma unroll
    for (int mi = 0; mi < 4; ++mi) {
#pragma unroll
        for (int rI = 0; rI < 4; ++rI) {
            const int d = dbase + wr * 64 + mi * 16 + lg * 4 + rI;
            const float bv = bg[d];
            float m = 0.f;
#pragma unroll
            for (int ni = 0; ni < 4; ++ni) {
                int win = i0 + wc * 64 + ni * 16 + lr;
                float v = acc[mi][ni][rI] + bv;
                v = fmaxf(v, 0.f);
                if (win >= Nw) v = 0.f;
                m = fmaxf(m, v);
            }
#pragma unroll
            for (int off = 1; off < 16; off <<= 1)
                m = fmaxf(m, __shfl_xor(m, off));
            if (lr == 0)
                atomicMax((int*)(out + ob + d), __float_as_int(m));
        }
    }
}

// ---------------- launch ----------------

extern "C" void kernel_launch(void* const* d_in, const int* in_sizes, int n_in,
                              void* d_out, int out_size, void* d_ws, size_t ws_size,
                              hipStream_t stream) {
    const float* x  = (const float*)d_in[0];
    const float* W1 = (const float*)d_in[1];
    const float* W2 = (const float*)d_in[2];
    const float* W3 = (const float*)d_in[3];
    const float* b1 = (const float*)d_in[4];
    const float* b2 = (const float*)d_in[5];
    const float* b3 = (const float*)d_in[6];
    float* out = (float*)d_out;

    hipMemsetAsync(d_out, 0, (size_t)out_size * sizeof(float), stream);

    const size_t need = (size_t)NCHT * 8192 * 2;         // W blob only: ~1.9 MB

    if (ws_size >= need) {
        unsigned short* wbb = (unsigned short*)d_ws;
        pack_w_kernel<<<472, 256, 0, stream>>>(W1, W2, W3, wbb); // 120,832/256 exact
        convgemm_kernel<<<NBLK, 1024, 0, stream>>>(x, wbb, b1, b2, b3, out);
    } else {
        dim3 grid(64, 8, 3);
        convmax_fallback<<<grid, 256, 0, stream>>>(x, W1, W2, W3, b1, b2, b3, out);
    }
}